// Round 1
// baseline (919.682 us; speedup 1.0000x reference)
//
#include <hip/hip_runtime.h>
#include <hip/hip_bf16.h>

#define NN 10000
#define NE 50000
#define FIN 40
#define FE 10
// L = 64

__device__ __forceinline__ float bcast(float v, int lane) {
    return __uint_as_float(__builtin_amdgcn_readlane(__float_as_uint(v), lane));
}

// ---------------- CSR build ----------------
__global__ void k_count(const int* __restrict__ ei, int* __restrict__ deg) {
    int e = blockIdx.x * 256 + threadIdx.x;
    if (e < NE) atomicAdd(&deg[ei[NE + e]], 1);
}

__global__ __launch_bounds__(1024) void k_scan(const int* __restrict__ deg,
                                               int* __restrict__ rowp,
                                               int* __restrict__ fill,
                                               float* __restrict__ invd) {
    __shared__ int buf[1024];
    int tid = threadIdx.x;
    int carry = 0;
    for (int base = 0; base < NN; base += 1024) {
        int idx = base + tid;
        int v = (idx < NN) ? deg[idx] : 0;
        buf[tid] = v;
        __syncthreads();
        for (int off = 1; off < 1024; off <<= 1) {
            int t = (tid >= off) ? buf[tid - off] : 0;
            __syncthreads();
            buf[tid] += t;
            __syncthreads();
        }
        int excl = buf[tid] - v;
        if (idx < NN) {
            rowp[idx] = carry + excl;
            fill[idx] = carry + excl;
            invd[idx] = 1.0f / (float)(v > 0 ? v : 1);
        }
        __syncthreads();
        carry += buf[1023];
        __syncthreads();
    }
    if (tid == 0) rowp[NN] = NE;
}

__global__ void k_fill(const int* __restrict__ ei, int* __restrict__ fill,
                       int* __restrict__ csrs, int* __restrict__ csre) {
    int e = blockIdx.x * 256 + threadIdx.x;
    if (e < NE) {
        int d = ei[NE + e];
        int p = atomicAdd(&fill[d], 1);
        csrs[p] = ei[e];
        csre[p] = e;
    }
}

// ---------------- edge MLP: hE = relu(edge_attr @ nn1_w + nn1_b) ----------------
__global__ __launch_bounds__(256) void k_edge_h(const float* __restrict__ ea,
                                                const float* __restrict__ w1,
                                                const float* __restrict__ b1,
                                                float* __restrict__ hE) {
    int lane = threadIdx.x & 63, wv = threadIdx.x >> 6;
    int e = blockIdx.x * 4 + wv;
    float av = (lane < FE) ? ea[e * FE + lane] : 0.f;
    float acc = b1[lane];
#pragma unroll
    for (int j = 0; j < FE; ++j) acc += bcast(av, j) * w1[j * 64 + lane];
    hE[e * 64 + lane] = fmaxf(acc, 0.f);
}

// ---------------- lin0: F = relu(x @ lin0_w + b) ----------------
__global__ __launch_bounds__(256) void k_lin0(const float* __restrict__ x,
                                              const float* __restrict__ w0,
                                              const float* __restrict__ b0,
                                              float* __restrict__ F) {
    int lane = threadIdx.x & 63, wv = threadIdx.x >> 6;
    int n = blockIdx.x * 4 + wv;
    float xv = (lane < FIN) ? x[n * FIN + lane] : 0.f;
    float acc = b0[lane];
#pragma unroll
    for (int k = 0; k < FIN; ++k) acc += bcast(xv, k) * w0[k * 64 + lane];
    F[n * 64 + lane] = fmaxf(acc, 0.f);
}

// ---------------- fused NNConv: m = relu(agg*inv_deg + F@conv_root + conv_bias) ----------------
// B=4 dst nodes per block; wave w owns node (blockIdx*4+w) in phase A,
// then acts as k-quarter in phase B, then node slot again for the epilogue.
__global__ __launch_bounds__(256) void k_nnconv(
    const float* __restrict__ F, const float* __restrict__ hE,
    const int* __restrict__ rowp, const int* __restrict__ csrs,
    const int* __restrict__ csre,
    const float* __restrict__ W2, const float* __restrict__ B2,
    const float* __restrict__ invd,
    const float* __restrict__ Wroot, const float* __restrict__ broot,
    float* __restrict__ M) {
    __shared__ float Gs[4][65][64];
    __shared__ float red[4][256];
    int tid = threadIdx.x;
    int lane = tid & 63, wv = tid >> 6;
    int d = blockIdx.x * 4 + wv;

    // phase A: accumulate G[k][i] = sum_e h_ek * u_i  (lane = i, regs over k)
    float G[64];
#pragma unroll
    for (int k = 0; k < 64; ++k) G[k] = 0.f;
    float usum = 0.f;
    int beg = rowp[d], end = rowp[d + 1];
    for (int p = beg; p < end; ++p) {
        int s = csrs[p], e = csre[p];
        float u = F[s * 64 + lane];
        float hv = hE[e * 64 + lane];
        usum += u;
#pragma unroll
        for (int k = 0; k < 64; ++k) G[k] += bcast(hv, k) * u;
    }
#pragma unroll
    for (int k = 0; k < 64; ++k) Gs[wv][k][lane] = G[k];
    Gs[wv][64][lane] = usum;
    __syncthreads();

    // phase B: contract with W2; lane = o, wave = k-quarter; 4 nodes share each W2 load
    float acc0 = 0.f, acc1 = 0.f, acc2 = 0.f, acc3 = 0.f;
    int o = lane;
    for (int k = wv * 16; k < wv * 16 + 16; ++k) {
        const float* w2row = &W2[k * 4096 + o];
        const float4* g0 = (const float4*)(&Gs[0][k][0]);
        const float4* g1 = (const float4*)(&Gs[1][k][0]);
        const float4* g2 = (const float4*)(&Gs[2][k][0]);
        const float4* g3 = (const float4*)(&Gs[3][k][0]);
#pragma unroll
        for (int i4 = 0; i4 < 16; ++i4) {
            float4 a0 = g0[i4], a1 = g1[i4], a2 = g2[i4], a3 = g3[i4];
            float wa = w2row[(i4 * 4 + 0) * 64];
            float wb = w2row[(i4 * 4 + 1) * 64];
            float wc = w2row[(i4 * 4 + 2) * 64];
            float wd = w2row[(i4 * 4 + 3) * 64];
            acc0 += a0.x * wa + a0.y * wb + a0.z * wc + a0.w * wd;
            acc1 += a1.x * wa + a1.y * wb + a1.z * wc + a1.w * wd;
            acc2 += a2.x * wa + a2.y * wb + a2.z * wc + a2.w * wd;
            acc3 += a3.x * wa + a3.y * wb + a3.z * wc + a3.w * wd;
        }
    }
    if (wv == 0) {  // nn2_b term: usum[i] * B2[i*64+o]
#pragma unroll 8
        for (int i = 0; i < 64; ++i) {
            float b2 = B2[i * 64 + o];
            acc0 += Gs[0][64][i] * b2;
            acc1 += Gs[1][64][i] * b2;
            acc2 += Gs[2][64][i] * b2;
            acc3 += Gs[3][64][i] * b2;
        }
    }
    red[wv][0 * 64 + o] = acc0;
    red[wv][1 * 64 + o] = acc1;
    red[wv][2 * 64 + o] = acc2;
    red[wv][3 * 64 + o] = acc3;
    __syncthreads();

    // epilogue: wave = node slot again
    float agg = red[0][wv * 64 + o] + red[1][wv * 64 + o] +
                red[2][wv * 64 + o] + red[3][wv * 64 + o];
    agg *= invd[d];
    float r = broot[o];
    float fv = F[d * 64 + lane];
#pragma unroll
    for (int k = 0; k < 64; ++k) r += bcast(fv, k) * Wroot[k * 64 + o];
    M[d * 64 + o] = fmaxf(agg + r, 0.f);
}

// ---------------- GRU single step: F <- GRU(m, F) ----------------
__global__ __launch_bounds__(256) void k_gru(const float* __restrict__ M,
                                             float* __restrict__ F,
                                             const float* __restrict__ Wih,
                                             const float* __restrict__ Whh,
                                             const float* __restrict__ bih,
                                             const float* __restrict__ bhh) {
    int lane = threadIdx.x & 63, wv = threadIdx.x >> 6;
    int n = blockIdx.x * 4 + wv;
    float mv = M[n * 64 + lane];
    float hv = F[n * 64 + lane];
    float gr = bih[lane], gz = bih[64 + lane], gn = bih[128 + lane];
    float hr = bhh[lane], hz = bhh[64 + lane], hn = bhh[128 + lane];
#pragma unroll
    for (int k = 0; k < 64; ++k) {
        float mk = bcast(mv, k), hk = bcast(hv, k);
        const float* wi = &Wih[k * 192];
        const float* wh = &Whh[k * 192];
        gr += mk * wi[lane];
        gz += mk * wi[64 + lane];
        gn += mk * wi[128 + lane];
        hr += hk * wh[lane];
        hz += hk * wh[64 + lane];
        hn += hk * wh[128 + lane];
    }
    float r = 1.f / (1.f + __expf(-(gr + hr)));
    float z = 1.f / (1.f + __expf(-(gz + hz)));
    float ng = tanhf(gn + r * hn);
    F[n * 64 + lane] = (1.f - z) * ng + z * hv;
}

// ---------------- final: out = relu(F@lin1+b1) @ lin2 + b2 ----------------
__global__ __launch_bounds__(256) void k_final(const float* __restrict__ F,
                                               const float* __restrict__ W1,
                                               const float* __restrict__ b1f,
                                               const float* __restrict__ W2l,
                                               const float* __restrict__ b2f,
                                               float* __restrict__ out) {
    int lane = threadIdx.x & 63, wv = threadIdx.x >> 6;
    int n = blockIdx.x * 4 + wv;
    float fv = F[n * 64 + lane];
    float acc = b1f[lane];
#pragma unroll
    for (int k = 0; k < 64; ++k) acc += bcast(fv, k) * W1[k * 64 + lane];
    acc = fmaxf(acc, 0.f);
    float p = acc * W2l[lane];
#pragma unroll
    for (int off = 32; off; off >>= 1) p += __shfl_xor(p, off, 64);
    if (lane == 0) out[n] = p + b2f[0];
}

extern "C" void kernel_launch(void* const* d_in, const int* in_sizes, int n_in,
                              void* d_out, int out_size, void* d_ws, size_t ws_size,
                              hipStream_t stream) {
    const float* x = (const float*)d_in[0];
    const int* ei = (const int*)d_in[1];
    const float* ea = (const float*)d_in[2];
    const float* l0w = (const float*)d_in[3];
    const float* l0b = (const float*)d_in[4];
    const float* n1w = (const float*)d_in[5];
    const float* n1b = (const float*)d_in[6];
    const float* n2w = (const float*)d_in[7];
    const float* n2b = (const float*)d_in[8];
    const float* cr = (const float*)d_in[9];
    const float* cb = (const float*)d_in[10];
    const float* wih = (const float*)d_in[11];
    const float* whh = (const float*)d_in[12];
    const float* bih = (const float*)d_in[13];
    const float* bhh = (const float*)d_in[14];
    const float* l1w = (const float*)d_in[15];
    const float* l1b = (const float*)d_in[16];
    const float* l2w = (const float*)d_in[17];
    const float* l2b = (const float*)d_in[18];

    char* w = (char*)d_ws;
    size_t off = 0;
    float* F = (float*)(w + off); off += (size_t)NN * 64 * 4;        // 2.56 MB
    float* M = (float*)(w + off); off += (size_t)NN * 64 * 4;        // 2.56 MB
    float* hE = (float*)(w + off); off += (size_t)NE * 64 * 4;       // 12.8 MB
    float* invd = (float*)(w + off); off += (size_t)NN * 4;
    int* deg = (int*)(w + off); off += (size_t)NN * 4;
    int* rowp = (int*)(w + off); off += (size_t)(NN + 1) * 4 + 252; off &= ~(size_t)255;
    int* fill = (int*)(w + off); off += (size_t)NN * 4;
    int* csrs = (int*)(w + off); off += (size_t)NE * 4;
    int* csre = (int*)(w + off); off += (size_t)NE * 4;

    hipMemsetAsync(deg, 0, NN * 4, stream);
    k_count<<<(NE + 255) / 256, 256, 0, stream>>>(ei, deg);
    k_scan<<<1, 1024, 0, stream>>>(deg, rowp, fill, invd);
    k_fill<<<(NE + 255) / 256, 256, 0, stream>>>(ei, fill, csrs, csre);
    k_edge_h<<<NE / 4, 256, 0, stream>>>(ea, n1w, n1b, hE);
    k_lin0<<<NN / 4, 256, 0, stream>>>(x, l0w, l0b, F);
    for (int it = 0; it < 3; ++it) {
        k_nnconv<<<NN / 4, 256, 0, stream>>>(F, hE, rowp, csrs, csre, n2w, n2b,
                                             invd, cr, cb, M);
        k_gru<<<NN / 4, 256, 0, stream>>>(M, F, wih, whh, bih, bhh);
    }
    k_final<<<NN / 4, 256, 0, stream>>>(F, l1w, l1b, l2w, l2b, (float*)d_out);
}